// Round 3
// baseline (218.710 us; speedup 1.0000x reference)
//
#include <hip/hip_runtime.h>
#include <math.h>

// fab_penalty_ls_curve: curvature penalty over mirrored level-set field.
// R3: R1's proven batched-load structure (13 independent loads/point, high
// MLP — R2's register rotation collapsed MLP and went latency-bound, 62->150us)
// + R2's independent wins: fast-math (v_rcp/v_sqrt/minimax atan), interior/
// boundary template split, fp32 per-thread accumulation, fused atomic finish.
// Mirror-half trick (verified absmax 0.0): compute left half only, x2.

#define BLOCK_X 256
#define ROWS_PER 16

// atan(v / c) with v > 0, given rv ~= 1/v (reused from k = num*rv^3).
// Max abs error ~1e-5 rad; error budget is ~1e3x larger (2% on the sum).
__device__ __forceinline__ float fast_atan_ratio(float v, float c, float rv)
{
    const float rc = __builtin_amdgcn_rcpf(c);
    const float q  = v * rc;        // v/c (sign = sign(c))
    const float iq = c * rv;        // c/v = 1/q, no extra rcp
    const bool  big = fabsf(q) > 1.0f;
    const float t  = big ? iq : q;
    const float s  = t * t;
    float p = fmaf(s, -0.01172120f, 0.05265332f);
    p = fmaf(s, p, -0.11643287f);
    p = fmaf(s, p,  0.19354346f);
    p = fmaf(s, p, -0.33262347f);
    p = fmaf(s, p,  0.99997726f);
    const float at = p * t;
    const float hp = copysignf(1.57079632679f, q);
    return big ? (hp - at) : at;    // atan(q) = sign(q)*pi/2 - atan(1/q), |q|>1
}

template<bool INT>
__device__ __forceinline__ float compute_rows(
    const float* __restrict__ eps, int Hn, int Wn, int i0,
    int j, int jm, int jmm, int cjp, int cjpp,
    float rd, float syj, float sym, float syp)
{
    const float rd2 = 0.5f * rd;
    const float SC = 1e-12f;
    const float FLOORV = (float)(1e-32 / 6.0);
    const float pi_d = 3.14159265358979323846f / 1.1f;

    float acc = 0.0f;
    for (int r = 0; r < ROWS_PER; ++r) {
        const int i = i0 + r;
        int im, ip, imm, ipp;
        float sxi, sxm, sxp;
        if (INT) {
            im = i - 1; ip = i + 1; imm = i - 2; ipp = i + 2;
            sxi = rd2; sxm = rd2; sxp = rd2;
        } else {
            im  = (i > 0) ? i - 1 : 0;
            ip  = (i < Hn - 1) ? i + 1 : Hn - 1;
            imm = (im > 0) ? im - 1 : 0;
            ipp = (ip < Hn - 1) ? ip + 1 : Hn - 1;
            sxi = (i == 0 || i == Hn - 1) ? rd : rd2;
            sxm = (im == 0) ? rd : rd2;
            sxp = (ip == Hn - 1) ? rd : rd2;
        }

        const float* rowc  = eps + (size_t)i   * (size_t)Wn;
        const float* rown  = eps + (size_t)im  * (size_t)Wn;
        const float* rows_ = eps + (size_t)ip  * (size_t)Wn;
        const float* rownn = eps + (size_t)imm * (size_t)Wn;
        const float* rowss = eps + (size_t)ipp * (size_t)Wn;

        // 13 independent loads, batched (keeps MLP high — do NOT rotate)
        const float e_c  = rowc[j];
        const float e_n  = rown[j],   e_s  = rows_[j];
        const float e_nn = rownn[j],  e_ss = rowss[j];
        const float e_w  = rowc[jm],  e_e  = rowc[cjp];
        const float e_ww = rowc[jmm], e_ee = rowc[cjpp];
        const float e_nw = rown[jm],  e_ne = rown[cjp];
        const float e_sw = rows_[jm], e_se = rows_[cjp];

        // first derivatives at (i,j)
        const float ex = fmaf(e_s - e_n, sxi, SC);
        const float ey = fmaf(e_e - e_w, syj, SC);

        // eps_x at rows im/ip (for eps_xx)
        float exn = fmaf(e_c - e_nn, sxm, SC);
        float exs = fmaf(e_ss - e_c, sxp, SC);
        if (!INT) {
            if (i == 0)      exn = ex;   // im == i at top boundary
            if (i == Hn - 1) exs = ex;   // ip == i at bottom boundary
        }
        const float exx = (exs - exn) * sxi;

        // eps_y at cols jm/jp (for eps_yy)
        float eyw = fmaf(e_c - e_ww, sym, SC);
        const float eye = fmaf(e_ee - e_c, syp, SC);
        if (j == 0) eyw = ey;            // jm == j at left boundary
        const float eyy = (eye - eyw) * syj;

        // eps_xy = Dy(eps_x); the +SC cancels in the difference
        const float exy = ((e_se - e_ne) - (e_sw - e_nw)) * (sxi * syj);

        const float t1 = ex * ex;
        const float t2 = ey * ey;
        float num = t1 * eyy;
        num = fmaf(t2, exx, num);
        num = fmaf(-2.0f * (ex * ey), exy, num);

        float ev = __builtin_amdgcn_sqrtf(t1 + t2);
        ev = fmaxf(ev, FLOORV);
        const float rv = __builtin_amdgcn_rcpf(ev);
        const float k  = num * (rv * rv) * rv;
        const float at = fast_atan_ratio(ev, e_c, rv);
        const float cc = fabsf(k * at) - pi_d;
        acc += fmaxf(cc, 0.0f);          // fmax(NaN,0)=0 -> nansum semantics
    }
    return acc;
}

__global__ __launch_bounds__(BLOCK_X) void curve_kernel(
    const float* __restrict__ eps, const float* __restrict__ gs,
    double* __restrict__ ws, float* __restrict__ out,
    int Hn, int Wn, int nblocks)
{
    const int tx = threadIdx.x;
    const int j  = blockIdx.x * BLOCK_X + tx;
    const int i0 = blockIdx.y * ROWS_PER;
    const float d  = gs[0];
    const float rd = 1.0f / d;
    const float rd2 = 0.5f * rd;

    float accf = 0.0f;
    if (j < Wn) {
        const int jm  = (j > 0) ? j - 1 : 0;
        const int jmm = (j > 1) ? j - 2 : 0;
        const int jp = j + 1, jpp = j + 2;
        const int cjp  = (jp  < Wn) ? jp  : (2 * Wn - 1 - jp);   // mirror seam
        const int cjpp = (jpp < Wn) ? jpp : (2 * Wn - 1 - jpp);
        const float syj = (j == 0)  ? rd : rd2;
        const float sym = (jm == 0) ? rd : rd2;
        const float syp = rd2;   // jp never a boundary of the 2W virtual grid

        const bool interior = (i0 >= 2) && (i0 + ROWS_PER + 1 < Hn);
        if (interior)
            accf = compute_rows<true >(eps, Hn, Wn, i0, j, jm, jmm, cjp, cjpp, rd, syj, sym, syp);
        else
            accf = compute_rows<false>(eps, Hn, Wn, i0, j, jm, jmm, cjp, cjpp, rd, syj, sym, syp);
    }

    double acc = (double)accf;
    #pragma unroll
    for (int off = 32; off > 0; off >>= 1)
        acc += __shfl_down(acc, off, 64);
    __shared__ double lds[BLOCK_X / 64];
    const int lane = tx & 63, wv = tx >> 6;
    if (lane == 0) lds[wv] = acc;
    __syncthreads();
    if (tx == 0) {
        double s = lds[0] + lds[1] + lds[2] + lds[3];
        __hip_atomic_fetch_add(ws, s, __ATOMIC_RELAXED, __HIP_MEMORY_SCOPE_AGENT);
        unsigned int old = __hip_atomic_fetch_add((unsigned int*)(ws + 1), 1u,
                                                  __ATOMIC_ACQ_REL, __HIP_MEMORY_SCOPE_AGENT);
        if (old == (unsigned int)nblocks - 1) {
            // all block partials are in; x2 for mirror half, x d^2 (ALPHA=1)
            double tot = __hip_atomic_load(ws, __ATOMIC_ACQUIRE, __HIP_MEMORY_SCOPE_AGENT);
            const double dd = (double)d;
            out[0] = (float)(tot * 2.0 * dd * dd);
        }
    }
}

extern "C" void kernel_launch(void* const* d_in, const int* in_sizes, int n_in,
                              void* d_out, int out_size, void* d_ws, size_t ws_size,
                              hipStream_t stream) {
    const float* eps = (const float*)d_in[0];
    const float* gs  = (const float*)d_in[1];
    float* out = (float*)d_out;

    const int n = in_sizes[0];
    int Wn = (int)(sqrt((double)n) + 0.5);   // 4096 for 4096x4096
    int Hn = n / Wn;

    const int gx = (Wn + BLOCK_X - 1) / BLOCK_X;     // 16
    const int gy = (Hn + ROWS_PER - 1) / ROWS_PER;   // 256

    // ws[0] = f64 total, ws+8 = arrival counter — zeroed every (graph) launch
    hipMemsetAsync(d_ws, 0, 16, stream);
    curve_kernel<<<dim3(gx, gy), BLOCK_X, 0, stream>>>(
        eps, gs, (double*)d_ws, out, Hn, Wn, gx * gy);
}

// Round 4
// 120.067 us; speedup vs baseline: 1.8216x; 1.8216x over previous
//
#include <hip/hip_runtime.h>
#include <math.h>

// fab_penalty_ls_curve: curvature penalty over mirrored level-set field.
// R4: R3 compute body (fast math, batched 13-load stencil, template split,
// fp32 per-thread accum) + R1's reduction plumbing (plain per-block partial
// stores -> tiny finish kernel). R2/R3's fused device-scope atomic finish
// (f64 add + ACQ_REL counter per block) is the suspected 3x regression:
// same-address atomic serialization + coherence traffic poisoning L1 reuse.
// Mirror-half trick (verified absmax 0.0): compute left half only, x2.

#define BLOCK_X 256
#define ROWS_PER 16

// atan(v / c) with v > 0, given rv ~= 1/v (reused from k = num*rv^3).
// Max abs error ~1e-5 rad; error budget is ~1e3x larger (2% on the sum).
__device__ __forceinline__ float fast_atan_ratio(float v, float c, float rv)
{
    const float rc = __builtin_amdgcn_rcpf(c);
    const float q  = v * rc;        // v/c (sign = sign(c))
    const float iq = c * rv;        // c/v = 1/q, no extra rcp
    const bool  big = fabsf(q) > 1.0f;
    const float t  = big ? iq : q;
    const float s  = t * t;
    float p = fmaf(s, -0.01172120f, 0.05265332f);
    p = fmaf(s, p, -0.11643287f);
    p = fmaf(s, p,  0.19354346f);
    p = fmaf(s, p, -0.33262347f);
    p = fmaf(s, p,  0.99997726f);
    const float at = p * t;
    const float hp = copysignf(1.57079632679f, q);
    return big ? (hp - at) : at;    // atan(q) = sign(q)*pi/2 - atan(1/q), |q|>1
}

template<bool INT>
__device__ __forceinline__ float compute_rows(
    const float* __restrict__ eps, int Hn, int Wn, int i0,
    int j, int jm, int jmm, int cjp, int cjpp,
    float rd, float syj, float sym, float syp)
{
    const float rd2 = 0.5f * rd;
    const float SC = 1e-12f;
    const float FLOORV = (float)(1e-32 / 6.0);
    const float pi_d = 3.14159265358979323846f / 1.1f;

    float acc = 0.0f;
    for (int r = 0; r < ROWS_PER; ++r) {
        const int i = i0 + r;
        int im, ip, imm, ipp;
        float sxi, sxm, sxp;
        if (INT) {
            im = i - 1; ip = i + 1; imm = i - 2; ipp = i + 2;
            sxi = rd2; sxm = rd2; sxp = rd2;
        } else {
            im  = (i > 0) ? i - 1 : 0;
            ip  = (i < Hn - 1) ? i + 1 : Hn - 1;
            imm = (im > 0) ? im - 1 : 0;
            ipp = (ip < Hn - 1) ? ip + 1 : Hn - 1;
            sxi = (i == 0 || i == Hn - 1) ? rd : rd2;
            sxm = (im == 0) ? rd : rd2;
            sxp = (ip == Hn - 1) ? rd : rd2;
        }

        const float* rowc  = eps + (size_t)i   * (size_t)Wn;
        const float* rown  = eps + (size_t)im  * (size_t)Wn;
        const float* rows_ = eps + (size_t)ip  * (size_t)Wn;
        const float* rownn = eps + (size_t)imm * (size_t)Wn;
        const float* rowss = eps + (size_t)ipp * (size_t)Wn;

        // 13 independent loads, batched (keeps MLP high)
        const float e_c  = rowc[j];
        const float e_n  = rown[j],   e_s  = rows_[j];
        const float e_nn = rownn[j],  e_ss = rowss[j];
        const float e_w  = rowc[jm],  e_e  = rowc[cjp];
        const float e_ww = rowc[jmm], e_ee = rowc[cjpp];
        const float e_nw = rown[jm],  e_ne = rown[cjp];
        const float e_sw = rows_[jm], e_se = rows_[cjp];

        // first derivatives at (i,j)
        const float ex = fmaf(e_s - e_n, sxi, SC);
        const float ey = fmaf(e_e - e_w, syj, SC);

        // eps_x at rows im/ip (for eps_xx)
        float exn = fmaf(e_c - e_nn, sxm, SC);
        float exs = fmaf(e_ss - e_c, sxp, SC);
        if (!INT) {
            if (i == 0)      exn = ex;   // im == i at top boundary
            if (i == Hn - 1) exs = ex;   // ip == i at bottom boundary
        }
        const float exx = (exs - exn) * sxi;

        // eps_y at cols jm/jp (for eps_yy)
        float eyw = fmaf(e_c - e_ww, sym, SC);
        const float eye = fmaf(e_ee - e_c, syp, SC);
        if (j == 0) eyw = ey;            // jm == j at left boundary
        const float eyy = (eye - eyw) * syj;

        // eps_xy = Dy(eps_x); the +SC cancels in the difference
        const float exy = ((e_se - e_ne) - (e_sw - e_nw)) * (sxi * syj);

        const float t1 = ex * ex;
        const float t2 = ey * ey;
        float num = t1 * eyy;
        num = fmaf(t2, exx, num);
        num = fmaf(-2.0f * (ex * ey), exy, num);

        float ev = __builtin_amdgcn_sqrtf(t1 + t2);
        ev = fmaxf(ev, FLOORV);
        const float rv = __builtin_amdgcn_rcpf(ev);
        const float k  = num * (rv * rv) * rv;
        const float at = fast_atan_ratio(ev, e_c, rv);
        const float cc = fabsf(k * at) - pi_d;
        acc += fmaxf(cc, 0.0f);          // fmax(NaN,0)=0 -> nansum semantics
    }
    return acc;
}

__global__ __launch_bounds__(BLOCK_X) void curve_partial_kernel(
    const float* __restrict__ eps, const float* __restrict__ gs,
    double* __restrict__ partial, int Hn, int Wn)
{
    const int tx = threadIdx.x;
    const int j  = blockIdx.x * BLOCK_X + tx;
    const int i0 = blockIdx.y * ROWS_PER;
    const float d  = gs[0];
    const float rd = 1.0f / d;
    const float rd2 = 0.5f * rd;

    float accf = 0.0f;
    {
        const int jm  = (j > 0) ? j - 1 : 0;
        const int jmm = (j > 1) ? j - 2 : 0;
        const int jp = j + 1, jpp = j + 2;
        const int cjp  = (jp  < Wn) ? jp  : (2 * Wn - 1 - jp);   // mirror seam
        const int cjpp = (jpp < Wn) ? jpp : (2 * Wn - 1 - jpp);
        const float syj = (j == 0)  ? rd : rd2;
        const float sym = (jm == 0) ? rd : rd2;
        const float syp = rd2;   // jp never a boundary of the 2W virtual grid

        const bool interior = (i0 >= 2) && (i0 + ROWS_PER + 1 < Hn);
        if (interior)
            accf = compute_rows<true >(eps, Hn, Wn, i0, j, jm, jmm, cjp, cjpp, rd, syj, sym, syp);
        else
            accf = compute_rows<false>(eps, Hn, Wn, i0, j, jm, jmm, cjp, cjpp, rd, syj, sym, syp);
    }

    double acc = (double)accf;
    #pragma unroll
    for (int off = 32; off > 0; off >>= 1)
        acc += __shfl_down(acc, off, 64);
    __shared__ double lds[BLOCK_X / 64];
    const int lane = tx & 63, wv = tx >> 6;
    if (lane == 0) lds[wv] = acc;
    __syncthreads();
    if (tx == 0) {
        // plain store — NO device-scope atomics (R2/R3's 3x regression)
        partial[blockIdx.y * gridDim.x + blockIdx.x] =
            lds[0] + lds[1] + lds[2] + lds[3];
    }
}

__global__ __launch_bounds__(256) void curve_finish_kernel(
    const double* __restrict__ partial, int n,
    const float* __restrict__ gs, float* __restrict__ out)
{
    const int tx = threadIdx.x;
    double acc = 0.0;
    for (int idx = tx; idx < n; idx += 256) acc += partial[idx];
    #pragma unroll
    for (int off = 32; off > 0; off >>= 1)
        acc += __shfl_down(acc, off, 64);
    __shared__ double lds[4];
    const int lane = tx & 63, wv = tx >> 6;
    if (lane == 0) lds[wv] = acc;
    __syncthreads();
    if (tx == 0) {
        const double d = (double)gs[0];
        // x2 for the mirrored half; x d^2 for grid_size^2 (ALPHA=1)
        out[0] = (float)((lds[0] + lds[1] + lds[2] + lds[3]) * 2.0 * d * d);
    }
}

extern "C" void kernel_launch(void* const* d_in, const int* in_sizes, int n_in,
                              void* d_out, int out_size, void* d_ws, size_t ws_size,
                              hipStream_t stream) {
    const float* eps = (const float*)d_in[0];
    const float* gs  = (const float*)d_in[1];
    float* out = (float*)d_out;

    const int n = in_sizes[0];
    int Wn = (int)(sqrt((double)n) + 0.5);   // 4096 for 4096x4096
    int Hn = n / Wn;

    const int gx = (Wn + BLOCK_X - 1) / BLOCK_X;     // 16
    const int gy = (Hn + ROWS_PER - 1) / ROWS_PER;   // 256
    double* partial = (double*)d_ws;   // gx*gy slots, ALL written every launch

    curve_partial_kernel<<<dim3(gx, gy), BLOCK_X, 0, stream>>>(eps, gs, partial, Hn, Wn);
    curve_finish_kernel<<<1, 256, 0, stream>>>(partial, gx * gy, gs, out);
}